// Round 14
// baseline (170.466 us; speedup 1.0000x reference)
//
#include <hip/hip_runtime.h>
#include <hip/hip_bf16.h>

#define B_SZ 8192
#define IH   2048
#define H_SZ 1024
#define BM   256            // rows per block
#define BK   32             // K per tile (4 chunks of 8 bf16 = 64 B)
#define NKT  (IH / BK)      // 64 K-tiles
#define WBUF 16384          // one W buf: [4 chunks][256 nrt] x 16B

typedef __attribute__((ext_vector_type(8)))  short  short8;
typedef __attribute__((ext_vector_type(16))) float  floatx16;

static __device__ __forceinline__ ushort f2bf(float f) {
  union { float f; unsigned u; } v; v.f = f;
  unsigned u = v.u;
  u += 0x7fffu + ((u >> 16) & 1u);   // RNE
  return (ushort)(u >> 16);
}
static __device__ __forceinline__ float sigmoidf_(float x) {
  return 1.0f / (1.0f + __expf(-x));
}
static __device__ __forceinline__ float tanhf_(float x) {
  float ax = fabsf(x);
  float e = __expf(-2.0f * ax);
  float t = (1.0f - e) / (1.0f + e);
  return copysignf(t, x);
}
static __device__ __forceinline__ void gload_lds16(const void* gsrc, void* ldst) {
  __builtin_amdgcn_global_load_lds(
      (__attribute__((address_space(1))) const void*)gsrc,
      (__attribute__((address_space(3))) void*)ldst, 16, 0, 0);
}

// ---------------------------------------------------------------------------
// Pre-pass 1: W[k][n] fp32 -> Wt2 k-chunk-major bf16:
//   slot (gck, gate, n) at ushort offset ((gck*4 + gate)*1024 + n)*8
//   holds W_gate[k = 8*gck .. 8*gck+8)[n].   gck in [0,256).
// ---------------------------------------------------------------------------
__global__ __launch_bounds__(256) void convert_w2_kernel(
    const float* __restrict__ Wf, const float* __restrict__ Wi,
    const float* __restrict__ Wo, const float* __restrict__ Wc,
    ushort* __restrict__ Wt2) {
  __shared__ float tile[64][65];
  const int g  = blockIdx.z;
  const float* W = (g == 0) ? Wf : (g == 1) ? Wi : (g == 2) ? Wo : Wc;
  const int n0 = blockIdx.x * 64;
  const int k0 = blockIdx.y * 64;
  const int tid = threadIdx.x;
#pragma unroll
  for (int i = 0; i < 4; ++i) {
    int c = i * 256 + tid;
    int r = c >> 4, c4 = c & 15;
    float4 v = *(const float4*)(W + (size_t)(k0 + r) * H_SZ + n0 + c4 * 4);
    tile[r][c4 * 4 + 0] = v.x;
    tile[r][c4 * 4 + 1] = v.y;
    tile[r][c4 * 4 + 2] = v.z;
    tile[r][c4 * 4 + 3] = v.w;
  }
  __syncthreads();
#pragma unroll
  for (int i = 0; i < 2; ++i) {
    int u  = i * 256 + tid;
    int kc = u >> 6;          // 0..7
    int n  = u & 63;
    ushort o[8] __attribute__((aligned(16)));
#pragma unroll
    for (int e = 0; e < 8; ++e) o[e] = f2bf(tile[kc * 8 + e][n]);
    ushort* dst = Wt2 + (((size_t)(k0 / 8 + kc) * 4 + g) * 1024 + n0 + n) * 8;
    *(uint4*)dst = *(uint4*)&o[0];
  }
}

// ---------------------------------------------------------------------------
// Pre-pass 2: A = [x | h_prev] fp32 -> Abf2 k-chunk-major bf16:
//   slot (gck, row) at ushort offset (gck*8192 + row)*8 holds
//   A[row][k = 8*gck .. +8).   gck in [0,256), row in [0,8192).
// ---------------------------------------------------------------------------
__global__ __launch_bounds__(256) void convert_a2_kernel(
    const float* __restrict__ x, const float* __restrict__ hp,
    ushort* __restrict__ Abf2) {
  __shared__ float tile[64][65];
  const int k0 = blockIdx.x * 64;
  const int r0 = blockIdx.y * 64;
  const int tid = threadIdx.x;
  const float* base = (k0 < 1024) ? x : hp;
  const int koff = (k0 < 1024) ? k0 : (k0 - 1024);
#pragma unroll
  for (int i = 0; i < 4; ++i) {
    int c = i * 256 + tid;
    int r = c >> 4, c4 = c & 15;
    float4 v = *(const float4*)(base + (size_t)(r0 + r) * 1024 + koff + c4 * 4);
    tile[r][c4 * 4 + 0] = v.x;
    tile[r][c4 * 4 + 1] = v.y;
    tile[r][c4 * 4 + 2] = v.z;
    tile[r][c4 * 4 + 3] = v.w;
  }
  __syncthreads();
#pragma unroll
  for (int i = 0; i < 2; ++i) {
    int u  = i * 256 + tid;
    int kc = u >> 6;          // 0..7
    int r  = u & 63;
    ushort o[8] __attribute__((aligned(16)));
#pragma unroll
    for (int e = 0; e < 8; ++e) o[e] = f2bf(tile[r][kc * 8 + e]);
    ushort* dst = Abf2 + ((size_t)(k0 / 8 + kc) * 8192 + r0 + r) * 8;
    *(uint4*)dst = *(uint4*)&o[0];
  }
}

// ---------------------------------------------------------------------------
// Fused 4-gate GEMM + LSTM epilogue — 32x32x16 MFMA, k-chunk-major operands.
//
// Block 256 rows x 256 fused cols; 8 waves = 4M x 2N; wave 64 x 128 =
// 2 m-tiles(32) x 4 n-tiles(32) = gate 0..3.  acc[2 mt][4 gate] f32x16.
//
// A: DIRECT from global Abf2 into ping-pong registers (no LDS). k-major
//   layout makes the fragment load 512B-contiguous per half-wave
//   (lane: row = b0+wm*64+mt*32+(ln&31), chunk = 2ks+(ln>>5)) — coalesced.
//   Loaded one window ahead; retired by the window-end vmcnt(0).
// W: LDS double buffer, [chunk 0..3][nrt 0..255]x16B per buf (16 KiB);
//   staged via gload_lds from k-major Wt2 (contiguous source, linear dest);
//   fragment reads are 32-consecutive-slot reads — conflict-free, no swizzle.
//
// Window w: RDSET_B(W-frags for w+1, from buf[(w+1)&1]);
//           LOADA(A(w+1) -> other reg set);
//           STAGE_W(tile (w+2)&63 -> buf[w&1]);
//           MFALL(tile w, 16 x mfma_f32_32x32x16_bf16);
//           lgkmcnt(0); vmcnt(0); s_barrier.
// Ledger (r13-verified skeleton): WAR: buf[w&1] (tile w) was read in window
//   w-1, retired by lgkmcnt(0)@BAR(w-1) in all waves; stage issues after.
//   RAW: tile w+2's stage + A(w+1) loads retired by vmcnt(0)@BAR(w).
//   A regs wave-private. Tail reads/stages wrap &63 = dead data.
// C/D layout (m74/m101, HW-verified): col = lane&31,
//   row = (reg&3) + 8*(reg>>2) + 4*(lane>>5).
// ---------------------------------------------------------------------------
__global__ __launch_bounds__(512, 2) void lstm_fused_kernel(
    const float* __restrict__ Cp, const ushort* __restrict__ Wt2,
    const ushort* __restrict__ Abf2,
    const float* __restrict__ bf_, const float* __restrict__ bi_,
    const float* __restrict__ bo_, const float* __restrict__ bc_,
    float* __restrict__ out) {
  __shared__ char lds[2 * WBUF];   // 32 KiB (W only)

  const int bid = blockIdx.x;
  const int wg  = (bid & 7) * 64 + (bid >> 3);   // bijective, 512 % 8 == 0
  const int b0  = (wg >> 4) * BM;                // 32 M-tiles
  const int n0g = (wg & 15) * 64;                // 16 N-tiles (64 cols/gate)

  const int tid = threadIdx.x;
  const int ln  = tid & 63;
  const int wv  = tid >> 6;
  const int wm  = wv >> 1, wn = wv & 1;

  floatx16 acc[2][4];
#pragma unroll
  for (int m = 0; m < 2; ++m)
#pragma unroll
    for (int j = 0; j < 4; ++j)
#pragma unroll
      for (int e = 0; e < 16; ++e) acc[m][j][e] = 0.f;

  // ---- A direct-load base (coalesced; deltas immediate) ----
  const char* Abf2B = (const char*)Abf2;
  const unsigned aG = (unsigned)(ln >> 5) * 131072u +
                      (unsigned)(b0 + wm * 64 + (ln & 31)) * 16u;
  // addr = Abf2B + aG + kt*524288 + ks*262144 + mt*512

  // ---- W ds_read base (conflict-free linear; deltas immediate) ----
  const int bRB = (ln >> 5) * 4096 + (wn * 32 + (ln & 31)) * 16;
  // addr = lds + db + bRB + ks*8192 + g*1024

  // ---- W stage constants ----
  const char* WtB = (const char*)Wt2;
  unsigned wS[2];
#pragma unroll
  for (int i = 0; i < 2; ++i) {
    int c    = 2 * i + (tid >> 8);        // chunk 0..3
    int nrt  = tid & 255;
    wS[i] = (unsigned)c * 65536u + (unsigned)(nrt >> 6) * 16384u +
            (unsigned)(n0g + (nrt & 63)) * 16u;
  }
  const int wdst0 = wv * 1024;            // wave-uniform LDS dest

#define STAGE_W(db, ktw)                                                      \
  do {                                                                        \
    gload_lds16(WtB + (wS[0] + (unsigned)(ktw)), lds + (db) + wdst0);         \
    gload_lds16(WtB + (wS[1] + (unsigned)(ktw)), lds + (db) + 8192 + wdst0);  \
  } while (0)

  short8 aFA[2][2], aFB[2][2];   // [mt][ks]
  short8 bFA[4][2], bFB[4][2];   // [gate][ks]
#define LOADA(AF, kta)                                                        \
  do {                                                                        \
    _Pragma("unroll")                                                         \
    for (int mt_ = 0; mt_ < 2; ++mt_)                                         \
      _Pragma("unroll")                                                       \
      for (int ks_ = 0; ks_ < 2; ++ks_)                                       \
        AF[mt_][ks_] = *(const short8*)(Abf2B + (aG + (unsigned)(kta) +       \
                         (unsigned)ks_ * 262144u + (unsigned)mt_ * 512u));    \
  } while (0)
#define RDSET_B(BF, db)                                                       \
  do {                                                                        \
    _Pragma("unroll")                                                         \
    for (int g_ = 0; g_ < 4; ++g_)                                            \
      _Pragma("unroll")                                                       \
      for (int ks_ = 0; ks_ < 2; ++ks_)                                       \
        BF[g_][ks_] = *(const short8*)(lds + (db) + bRB + ks_ * 8192 +        \
                                       g_ * 1024);                            \
  } while (0)
// 16 MFMA: ks outer, (mt,g) inner -> 8 apart between same-acc reuses.
#define MFALL(AF, BF)                                                         \
  do {                                                                        \
    __builtin_amdgcn_s_setprio(1);                                            \
    _Pragma("unroll")                                                         \
    for (int ks_ = 0; ks_ < 2; ++ks_)                                         \
      _Pragma("unroll")                                                       \
      for (int mt_ = 0; mt_ < 2; ++mt_)                                       \
        _Pragma("unroll")                                                     \
        for (int g_ = 0; g_ < 4; ++g_)                                        \
          acc[mt_][g_] = __builtin_amdgcn_mfma_f32_32x32x16_bf16(             \
              AF[mt_][ks_], BF[g_][ks_], acc[mt_][g_], 0, 0, 0);              \
    __builtin_amdgcn_s_setprio(0);                                            \
  } while (0)
#define BAR    __builtin_amdgcn_s_barrier()
#define LGKM0  asm volatile("s_waitcnt lgkmcnt(0)" ::: "memory")
#define VMC0   asm volatile("s_waitcnt vmcnt(0)" ::: "memory")

  // ---- prologue ----
  STAGE_W(0, 0);                 // tile 0 -> buf0
  STAGE_W(WBUF, 262144);         // tile 1 -> buf1
  LOADA(aFA, 0);                 // A(0)
  VMC0; BAR;
  RDSET_B(bFA, 0);               // W-frags(0)
  LGKM0; BAR;

#pragma unroll 1
  for (int it = 0; it < NKT / 2; ++it) {
    // window w = 2it: consume tile w (setA); prep w+1 (setB); stage w+2->buf0
    {
      const unsigned ktaN = (unsigned)((2 * it + 1) & 63) * 524288u;
      const unsigned ktwN = (unsigned)((2 * it + 2) & 63) * 262144u;
      RDSET_B(bFB, WBUF);
      LOADA(aFB, ktaN);
      STAGE_W(0, ktwN);
      MFALL(aFA, bFA);
      LGKM0; VMC0; BAR;
    }
    // window w = 2it+1: consume tile w (setB); prep w+1 (setA); stage w+2->buf1
    {
      const unsigned ktaN = (unsigned)((2 * it + 2) & 63) * 524288u;
      const unsigned ktwN = (unsigned)((2 * it + 3) & 63) * 262144u;
      RDSET_B(bFA, 0);
      LOADA(aFA, ktaN);
      STAGE_W(WBUF, ktwN);
      MFALL(aFB, bFB);
      LGKM0; VMC0; BAR;
    }
  }

  // ---- epilogue: acc[mt][gate]; col = ln&31, row per m74/m101 ----
  const int n = n0g + wn * 32 + (ln & 31);
  const float vbf = bf_[n], vbi = bi_[n], vbo = bo_[n], vbc = bc_[n];
  const int h2 = (ln >> 5) * 4;
  float* outh = out;
  float* outC = out + (size_t)B_SZ * H_SZ;
#pragma unroll
  for (int mt = 0; mt < 2; ++mt) {
#pragma unroll
    for (int reg = 0; reg < 16; ++reg) {
      int row = b0 + wm * 64 + mt * 32 + (reg & 3) + 8 * (reg >> 2) + h2;
      float fg = sigmoidf_(acc[mt][0][reg] + vbf);
      float ig = sigmoidf_(acc[mt][1][reg] + vbi);
      float og = sigmoidf_(acc[mt][2][reg] + vbo);
      float cg = tanhf_  (acc[mt][3][reg] + vbc);
      float cp = Cp[(size_t)row * H_SZ + n];
      float Ct = fg * cp + ig * cg;
      float ht = og * tanhf_(Ct);
      outh[(size_t)row * H_SZ + n] = ht;
      outC[(size_t)row * H_SZ + n] = Ct;
    }
  }
#undef STAGE_W
#undef LOADA
#undef RDSET_B
#undef MFALL
#undef BAR
#undef LGKM0
#undef VMC0
}

extern "C" void kernel_launch(void* const* d_in, const int* in_sizes, int n_in,
                              void* d_out, int out_size, void* d_ws, size_t ws_size,
                              hipStream_t stream) {
  const float* x  = (const float*)d_in[0];
  const float* hp = (const float*)d_in[1];
  const float* Cp = (const float*)d_in[2];
  const float* Wf = (const float*)d_in[3];
  const float* bf = (const float*)d_in[4];
  const float* Wi = (const float*)d_in[5];
  const float* bi = (const float*)d_in[6];
  const float* Wc = (const float*)d_in[7];
  const float* bc = (const float*)d_in[8];
  const float* Wo = (const float*)d_in[9];
  const float* bo = (const float*)d_in[10];

  ushort* Wt2  = (ushort*)d_ws;                          // 16 MiB, k-major
  ushort* Abf2 = (ushort*)((char*)d_ws + (16u << 20));   // 32 MiB, k-major

  dim3 gridW(16, 32, 4);          // (n-tiles, k-tiles, gates)
  convert_w2_kernel<<<gridW, 256, 0, stream>>>(Wf, Wi, Wo, Wc, Wt2);
  dim3 gridA(32, 128);            // (k-tiles, row-tiles)
  convert_a2_kernel<<<gridA, 256, 0, stream>>>(x, hp, Abf2);

  lstm_fused_kernel<<<512, 512, 0, stream>>>(Cp, Wt2, Abf2,
                                             bf, bi, bo, bc, (float*)d_out);
}